// Round 1
// baseline (171.716 us; speedup 1.0000x reference)
//
#include <hip/hip_runtime.h>
#include <math.h>

#define B_SZ 32
#define N_NODES 4096
#define C_DIM 64
#define M_EDGES 64
#define DEG 256
#define E_INC 16384
#define NEG_SLOPE 0.2f
#define MARGIN 4.2f

__device__ __forceinline__ float wsum64(float v) {
#pragma unroll
  for (int off = 32; off > 0; off >>= 1) v += __shfl_xor(v, off, 64);
  return v;
}

// xw[b,n,c] = sum_k x[b,n,k]*w[k,c]; fused s1[row] = dot(xw_row, att[0:64])
__global__ __launch_bounds__(256) void k_gemm(
    const float* __restrict__ x, const float* __restrict__ w,
    const float* __restrict__ att, float* __restrict__ xw,
    float* __restrict__ s1) {
  __shared__ float ws[64 * 64];
  __shared__ float xs[16 * 64];
  const int tid = threadIdx.x;
  const float4* w4 = (const float4*)w;
  float4* ws4 = (float4*)ws;
#pragma unroll
  for (int i = 0; i < 4; ++i) ws4[tid + 256 * i] = w4[tid + 256 * i];
  const int rowbase = blockIdx.x * 16;
  ((float4*)xs)[tid] = ((const float4*)(x + (size_t)rowbase * 64))[tid];
  __syncthreads();
  const int col = tid & 63, rg = tid >> 6;
  float acc0 = 0.f, acc1 = 0.f, acc2 = 0.f, acc3 = 0.f;
  const float* xr = xs + rg * 4 * 64;
#pragma unroll 16
  for (int k = 0; k < 64; ++k) {
    const float wv = ws[k * 64 + col];
    acc0 += xr[k] * wv;
    acc1 += xr[64 + k] * wv;
    acc2 += xr[128 + k] * wv;
    acc3 += xr[192 + k] * wv;
  }
  const float av = att[col];
  float acc[4] = {acc0, acc1, acc2, acc3};
#pragma unroll
  for (int j = 0; j < 4; ++j) {
    const int row = rg * 4 + j;
    xw[(size_t)(rowbase + row) * 64 + col] = acc[j];
    const float r = wsum64(acc[j] * av);
    if (col == 0) s1[rowbase + row] = r;
  }
}

// edge_sums[m,b,c] = sum over 256 incidences of xw[b,node,c]
// fused: s2[m,b]=dot(es,att[64:]), nrm2[m,b]=|es|^2, essum[m,b]=sum_c es
__global__ __launch_bounds__(256) void k_edge(
    const float* __restrict__ xw, const int* __restrict__ node_ids,
    const float* __restrict__ att, float* __restrict__ edge_sums,
    float* __restrict__ s2, float* __restrict__ nrm2,
    float* __restrict__ essum) {
  const int m = blockIdx.x, bq = blockIdx.y;
  const int tid = threadIdx.x;
  const int c = tid & 63;
  const int b = bq * 4 + (tid >> 6);
  const float* xwb = xw + (size_t)b * N_NODES * C_DIM;
  const int ebase = m * DEG;
  float acc = 0.f;
#pragma unroll 8
  for (int i = 0; i < DEG; ++i) {
    const int node = node_ids[ebase + i];
    acc += xwb[node * C_DIM + c];
  }
  edge_sums[(m * B_SZ + b) * C_DIM + c] = acc;
  const float sr = wsum64(acc * att[64 + c]);
  const float nr = wsum64(acc * acc);
  const float er = wsum64(acc);
  if (c == 0) {
    s2[m * B_SZ + b] = sr;
    nrm2[m * B_SZ + b] = nr;
    essum[m * B_SZ + b] = er;
  }
}

// lossbuf[k*64+m] = |mean_b(loss_item[k,m,b])|
__global__ __launch_bounds__(64) void k_loss(const float* __restrict__ es,
                                             const float* __restrict__ nrm2,
                                             float* __restrict__ lossbuf) {
  const int k = blockIdx.x >> 6, m = blockIdx.x & 63;
  const int c = threadIdx.x;
  float sum_li = 0.f;
  for (int b = 0; b < B_SZ; ++b) {
    const float ek = es[(k * B_SZ + b) * C_DIM + c];
    const float em = es[(m * B_SZ + b) * C_DIM + c];
    const float inner = wsum64(ek * em);
    const float d = ek - em;
    const float d2 = wsum64(d * d);
    const float nk = sqrtf(nrm2[k * B_SZ + b]);
    const float nm = sqrtf(nrm2[m * B_SZ + b]);
    const float cosv = inner / (nk * nm);
    const float dist = sqrtf(d2);
    const float li = cosv * dist + (1.f - cosv) * fmaxf(MARGIN - dist, 0.f);
    sum_li += li;
  }
  if (c == 0) lossbuf[blockIdx.x] = fabsf(sum_li * (1.f / 32.f));
}

__global__ void k_count(const int* __restrict__ node_ids, int* __restrict__ D) {
  const int e = blockIdx.x * 256 + threadIdx.x;
  if (e < E_INC) atomicAdd(&D[node_ids[e]], 1);
}

// exclusive scan of D[4096] -> row_ptr[4097], single block of 256
__global__ __launch_bounds__(256) void k_scan(const int* __restrict__ D,
                                              int* __restrict__ row_ptr) {
  __shared__ int tot[256];
  const int t = threadIdx.x;
  int loc[16];
  int run = 0;
#pragma unroll
  for (int i = 0; i < 16; ++i) {
    run += D[t * 16 + i];
    loc[i] = run;
  }
  tot[t] = run;
  __syncthreads();
  for (int off = 1; off < 256; off <<= 1) {
    int v = (t >= off) ? tot[t - off] : 0;
    __syncthreads();
    tot[t] += v;
    __syncthreads();
  }
  const int base = (t == 0) ? 0 : tot[t - 1];
  if (t == 0) row_ptr[0] = 0;
#pragma unroll
  for (int i = 0; i < 16; ++i) row_ptr[t * 16 + i + 1] = base + loc[i];
}

__global__ void k_fill(const int* __restrict__ node_ids,
                       const int* __restrict__ row_ptr, int* __restrict__ fill,
                       int* __restrict__ csr) {
  const int e = blockIdx.x * 256 + threadIdx.x;
  if (e >= E_INC) return;
  const int n = node_ids[e];
  const int pos = atomicAdd(&fill[n], 1);
  csr[row_ptr[n] + pos] = e;
}

// per-node segmented softmax -> alpha[e,b]
__global__ __launch_bounds__(64) void k_alpha(
    const int* __restrict__ row_ptr, const int* __restrict__ csr,
    const int* __restrict__ edge_ids, const float* __restrict__ s1,
    const float* __restrict__ s2, float* __restrict__ alpha) {
  const int n = blockIdx.x * 2 + (threadIdx.x >> 5);
  const int b = threadIdx.x & 31;
  const int rs = row_ptr[n], re = row_ptr[n + 1];
  if (rs == re) return;
  const float s1v = s1[b * N_NODES + n];
  float mx = -1e30f;
  for (int i = rs; i < re; ++i) {
    const int mm = edge_ids[csr[i]];
    float sc = s1v + s2[mm * B_SZ + b];
    sc = sc > 0.f ? sc : NEG_SLOPE * sc;
    mx = fmaxf(mx, sc);
  }
  float sum = 0.f;
  for (int i = rs; i < re; ++i) {
    const int mm = edge_ids[csr[i]];
    float sc = s1v + s2[mm * B_SZ + b];
    sc = sc > 0.f ? sc : NEG_SLOPE * sc;
    sum += expf(sc - mx);
  }
  const float inv = 1.f / sum;
  for (int i = rs; i < re; ++i) {
    const int e = csr[i];
    const int mm = edge_ids[e];
    float sc = s1v + s2[mm * B_SZ + b];
    sc = sc > 0.f ? sc : NEG_SLOPE * sc;
    alpha[e * B_SZ + b] = expf(sc - mx) * inv;
  }
}

// out_e[m,b,c] = (1/256) * sum_{e in edge m} alpha[e,b]*xw[b,node_e,c]
__global__ __launch_bounds__(256) void k_oute(
    const float* __restrict__ xw, const int* __restrict__ node_ids,
    const float* __restrict__ alpha, float* __restrict__ out_e) {
  const int m = blockIdx.x, bq = blockIdx.y;
  const int tid = threadIdx.x;
  const int c = tid & 63;
  const int b = bq * 4 + (tid >> 6);
  const float* xwb = xw + (size_t)b * N_NODES * C_DIM;
  const int ebase = m * DEG;
  float acc = 0.f;
#pragma unroll 8
  for (int i = 0; i < DEG; ++i) {
    const int node = node_ids[ebase + i];
    const float a = alpha[(ebase + i) * B_SZ + b];
    acc += a * xwb[node * C_DIM + c];
  }
  out_e[(m * B_SZ + b) * C_DIM + c] = acc * (1.0f / 256.0f);
}

// out[b,n,c] = D[n] * sum_{e in node n} alpha[e,b]*out_e[edge_e,b,c]
__global__ __launch_bounds__(256) void k_out(
    const int* __restrict__ row_ptr, const int* __restrict__ csr,
    const int* __restrict__ edge_ids, const float* __restrict__ alpha,
    const float* __restrict__ out_e, float* __restrict__ out) {
  const int n = blockIdx.x, bq = blockIdx.y;
  const int tid = threadIdx.x;
  const int c = tid & 63;
  const int b = bq * 4 + (tid >> 6);
  const int rs = row_ptr[n], re = row_ptr[n + 1];
  float acc = 0.f;
  for (int i = rs; i < re; ++i) {
    const int e = csr[i];
    const int m = edge_ids[e];
    acc += alpha[e * B_SZ + b] * out_e[(m * B_SZ + b) * C_DIM + c];
  }
  const float Dn = (float)(re - rs);
  out[((size_t)b * N_NODES + n) * C_DIM + c] = Dn * acc;
}

// deterministic final reductions + scalar output
__global__ __launch_bounds__(256) void k_fin(const float* __restrict__ essum,
                                             const float* __restrict__ lossbuf,
                                             float* __restrict__ outs) {
  __shared__ float sm[256];
  const int t = threadIdx.x;
  float s = 0.f;
  for (int i = t; i < M_EDGES * B_SZ; i += 256) s += essum[i];
  sm[t] = s;
  __syncthreads();
  for (int o = 128; o > 0; o >>= 1) {
    if (t < o) sm[t] += sm[t + o];
    __syncthreads();
  }
  const float S = sm[0];
  __syncthreads();
  float l = 0.f;
  for (int i = t; i < M_EDGES * M_EDGES; i += 256) l += lossbuf[i];
  sm[t] = l;
  __syncthreads();
  for (int o = 128; o > 0; o >>= 1) {
    if (t < o) sm[t] += sm[t + o];
    __syncthreads();
  }
  if (t == 0) {
    // sum(x_i - x_j) = S - 256*S = -255*S ; mean over E*B*C elements
    const float mean = S * (-255.0f) / 33554432.0f;
    outs[0] = fabsf(mean) + sm[0] * (1.0f / 4225.0f);
  }
}

extern "C" void kernel_launch(void* const* d_in, const int* in_sizes, int n_in,
                              void* d_out, int out_size, void* d_ws,
                              size_t ws_size, hipStream_t stream) {
  (void)in_sizes; (void)n_in; (void)out_size; (void)ws_size;
  const float* x = (const float*)d_in[0];
  const float* weight = (const float*)d_in[1];
  const float* att = (const float*)d_in[2];
  const int* hei = (const int*)d_in[3];
  const int* node_ids = hei;
  const int* edge_ids = hei + E_INC;
  float* out = (float*)d_out;
  float* xw = out;  // reuse d_out[0 .. B*N*C) as xw scratch; overwritten by k_out

  char* wsb = (char*)d_ws;
  float* edge_sums = (float*)(wsb);                  // 512KB
  float* out_e = (float*)(wsb + (512 << 10));        // 512KB
  float* s1 = (float*)(wsb + (1024 << 10));          // 512KB
  float* alpha = (float*)(wsb + (1536 << 10));       // 2MB
  float* s2 = (float*)(wsb + (3584 << 10));          // 8KB
  float* nrm2 = (float*)(wsb + (3592 << 10));        // 8KB
  float* essum = (float*)(wsb + (3600 << 10));       // 8KB
  float* lossbuf = (float*)(wsb + (3608 << 10));     // 16KB
  int* row_ptr = (int*)(wsb + (3624 << 10));         // 20KB (4097 ints)
  int* csr = (int*)(wsb + (3644 << 10));             // 64KB
  int* Dcnt = (int*)(wsb + (3708 << 10));            // 16KB
  int* fill = (int*)(wsb + (3724 << 10));            // 16KB

  hipMemsetAsync(wsb + (3708 << 10), 0, 32 << 10, stream);  // Dcnt + fill
  k_gemm<<<8192, 256, 0, stream>>>(x, weight, att, xw, s1);
  k_edge<<<dim3(M_EDGES, 8), 256, 0, stream>>>(xw, node_ids, att, edge_sums,
                                               s2, nrm2, essum);
  k_loss<<<M_EDGES * M_EDGES, 64, 0, stream>>>(edge_sums, nrm2, lossbuf);
  k_count<<<E_INC / 256, 256, 0, stream>>>(node_ids, Dcnt);
  k_scan<<<1, 256, 0, stream>>>(Dcnt, row_ptr);
  k_fill<<<E_INC / 256, 256, 0, stream>>>(node_ids, row_ptr, fill, csr);
  k_alpha<<<N_NODES / 2, 64, 0, stream>>>(row_ptr, csr, edge_ids, s1, s2,
                                          alpha);
  k_oute<<<dim3(M_EDGES, 8), 256, 0, stream>>>(xw, node_ids, alpha, out_e);
  k_out<<<dim3(N_NODES, 8), 256, 0, stream>>>(row_ptr, csr, edge_ids, alpha,
                                              out_e, out);
  k_fin<<<1, 256, 0, stream>>>(essum, lossbuf,
                               out + (size_t)B_SZ * N_NODES * C_DIM);
}

// Round 2
// 146.627 us; speedup vs baseline: 1.1711x; 1.1711x over previous
//
#include <hip/hip_runtime.h>
#include <math.h>

#define B_SZ 32
#define N_NODES 4096
#define C_DIM 64
#define M_EDGES 64
#define DEG 256
#define E_INC 16384
#define NEG_SLOPE 0.2f
#define MARGIN 4.2f
#define RPB 16  // rows per wave-block in k_gemm2

__device__ __forceinline__ float wsum64(float v) {
#pragma unroll
  for (int off = 32; off > 0; off >>= 1) v += __shfl_xor(v, off, 64);
  return v;
}

// xw[row,c] = sum_k x[row,k]*w[k,c]; s1[row] = dot(xw_row, att[0:64])
// One wave per block. W held in VGPRs (lane=col, 64 regs); x rows are
// wave-uniform -> compiler emits s_load (SGPR broadcast) -> pure v_fmac loop.
__global__ __launch_bounds__(64) void k_gemm2(const float* __restrict__ x,
                                              const float* __restrict__ w,
                                              const float* __restrict__ att,
                                              float* __restrict__ xw,
                                              float* __restrict__ s1) {
  const int lane = threadIdx.x;
  float wreg[64];
#pragma unroll
  for (int k = 0; k < 64; ++k) wreg[k] = w[k * 64 + lane];
  const float av = att[lane];
  const int row0 = blockIdx.x * RPB;
#pragma unroll 1
  for (int r = 0; r < RPB; ++r) {
    const int row = row0 + r;
    const float* __restrict__ xr = x + (size_t)row * 64;
    float acc = 0.f;
#pragma unroll
    for (int k = 0; k < 64; ++k) acc = fmaf(xr[k], wreg[k], acc);
    xw[(size_t)row * 64 + lane] = acc;
    const float sv = wsum64(acc * av);
    if (lane == 0) s1[row] = sv;
  }
}

// Build node-CSR in one block: LDS count -> LDS scan -> LDS-atomic fill.
__global__ __launch_bounds__(1024) void k_csr(const int* __restrict__ node_ids,
                                              int* __restrict__ row_ptr,
                                              int* __restrict__ csr) {
  __shared__ int cnt[N_NODES];
  __shared__ int rp[N_NODES];
  __shared__ int part[1024];
  const int t = threadIdx.x;
#pragma unroll
  for (int i = 0; i < 4; ++i) cnt[t + 1024 * i] = 0;
  __syncthreads();
#pragma unroll
  for (int i = 0; i < 16; ++i) atomicAdd(&cnt[node_ids[t + 1024 * i]], 1);
  __syncthreads();
  const int c0 = cnt[4 * t], c1 = cnt[4 * t + 1], c2 = cnt[4 * t + 2],
            c3 = cnt[4 * t + 3];
  const int tsum = c0 + c1 + c2 + c3;
  part[t] = tsum;
  __syncthreads();
  for (int off = 1; off < 1024; off <<= 1) {
    const int v = (t >= off) ? part[t - off] : 0;
    __syncthreads();
    part[t] += v;
    __syncthreads();
  }
  const int base = part[t] - tsum;  // exclusive
  rp[4 * t] = base;
  rp[4 * t + 1] = base + c0;
  rp[4 * t + 2] = base + c0 + c1;
  rp[4 * t + 3] = base + c0 + c1 + c2;
  // reset cnt for use as fill counters (barriers above ordered all reads)
#pragma unroll
  for (int i = 0; i < 4; ++i) cnt[t + 1024 * i] = 0;
  __syncthreads();
#pragma unroll
  for (int i = 0; i < 16; ++i) {
    const int e = t + 1024 * i;
    const int n = node_ids[e];
    const int pos = atomicAdd(&cnt[n], 1);
    csr[rp[n] + pos] = e;
  }
#pragma unroll
  for (int i = 0; i < 4; ++i) {
    const int idx = t + 1024 * i;
    row_ptr[idx] = rp[idx];
  }
  if (t == 0) row_ptr[N_NODES] = E_INC;
}

// edge sums, stored TRANSPOSED es_t[m,c,b]; fused s2/nrm2/essum reductions
__global__ __launch_bounds__(256) void k_edge(
    const float* __restrict__ xw, const int* __restrict__ node_ids,
    const float* __restrict__ att, float* __restrict__ es_t,
    float* __restrict__ s2, float* __restrict__ nrm2,
    float* __restrict__ essum) {
  const int m = blockIdx.x, bq = blockIdx.y;
  const int tid = threadIdx.x;
  const int c = tid & 63;
  const int b = bq * 4 + (tid >> 6);
  const float* xwb = xw + (size_t)b * N_NODES * C_DIM;
  const int ebase = m * DEG;
  float acc = 0.f;
#pragma unroll 16
  for (int i = 0; i < DEG; ++i) {
    const int node = node_ids[ebase + i];
    acc += xwb[node * C_DIM + c];
  }
  es_t[(m * C_DIM + c) * B_SZ + b] = acc;
  const float sr = wsum64(acc * att[64 + c]);
  const float nr = wsum64(acc * acc);
  const float er = wsum64(acc);
  if (c == 0) {
    s2[m * B_SZ + b] = sr;
    nrm2[m * B_SZ + b] = nr;
    essum[m * B_SZ + b] = er;
  }
}

// lossbuf[p] = |mean_b loss_item[k,m,b]| using lane-local c-reduction (lane=b)
// dist^2 = nk^2 + nm^2 - 2*inner  (no per-pair norm reduction needed)
__global__ __launch_bounds__(256) void k_loss2(const float* __restrict__ es_t,
                                               const float* __restrict__ nrm2,
                                               float* __restrict__ lossbuf) {
  const int p = blockIdx.x * 4 + (threadIdx.x >> 6);
  const int k = p >> 6, m = p & 63;
  const int b = threadIdx.x & 31;
  float inner = 0.f;
#pragma unroll 8
  for (int c = 0; c < C_DIM; ++c) {
    const float ek = es_t[(k * C_DIM + c) * B_SZ + b];
    const float em = es_t[(m * C_DIM + c) * B_SZ + b];
    inner = fmaf(ek, em, inner);
  }
  const float nk2 = nrm2[k * B_SZ + b];
  const float nm2 = nrm2[m * B_SZ + b];
  const float d2 = fmaxf(nk2 + nm2 - 2.f * inner, 0.f);
  const float dist = sqrtf(d2);
  const float cosv = inner / sqrtf(nk2 * nm2);
  float li = cosv * dist + (1.f - cosv) * fmaxf(MARGIN - dist, 0.f);
#pragma unroll
  for (int off = 16; off > 0; off >>= 1) li += __shfl_xor(li, off, 32);
  if ((threadIdx.x & 63) == 0) lossbuf[p] = fabsf(li * (1.f / 32.f));
}

// per-node segmented softmax -> alpha[e,b]
__global__ __launch_bounds__(64) void k_alpha(
    const int* __restrict__ row_ptr, const int* __restrict__ csr,
    const int* __restrict__ edge_ids, const float* __restrict__ s1,
    const float* __restrict__ s2, float* __restrict__ alpha) {
  const int n = blockIdx.x * 2 + (threadIdx.x >> 5);
  const int b = threadIdx.x & 31;
  const int rs = row_ptr[n], re = row_ptr[n + 1];
  if (rs == re) return;
  const float s1v = s1[b * N_NODES + n];
  float mx = -1e30f;
  for (int i = rs; i < re; ++i) {
    const int mm = edge_ids[csr[i]];
    float sc = s1v + s2[mm * B_SZ + b];
    sc = sc > 0.f ? sc : NEG_SLOPE * sc;
    mx = fmaxf(mx, sc);
  }
  float sum = 0.f;
  for (int i = rs; i < re; ++i) {
    const int mm = edge_ids[csr[i]];
    float sc = s1v + s2[mm * B_SZ + b];
    sc = sc > 0.f ? sc : NEG_SLOPE * sc;
    sum += expf(sc - mx);
  }
  const float inv = 1.f / sum;
  for (int i = rs; i < re; ++i) {
    const int e = csr[i];
    const int mm = edge_ids[e];
    float sc = s1v + s2[mm * B_SZ + b];
    sc = sc > 0.f ? sc : NEG_SLOPE * sc;
    alpha[e * B_SZ + b] = expf(sc - mx) * inv;
  }
}

// out_e[m,b,c] = (1/256) * sum_{e in edge m} alpha[e,b]*xw[b,node_e,c]
__global__ __launch_bounds__(256) void k_oute(
    const float* __restrict__ xw, const int* __restrict__ node_ids,
    const float* __restrict__ alpha, float* __restrict__ out_e) {
  const int m = blockIdx.x, bq = blockIdx.y;
  const int tid = threadIdx.x;
  const int c = tid & 63;
  const int b = bq * 4 + (tid >> 6);
  const float* xwb = xw + (size_t)b * N_NODES * C_DIM;
  const int ebase = m * DEG;
  float acc = 0.f;
#pragma unroll 16
  for (int i = 0; i < DEG; ++i) {
    const int node = node_ids[ebase + i];
    const float a = alpha[(ebase + i) * B_SZ + b];
    acc = fmaf(a, xwb[node * C_DIM + c], acc);
  }
  out_e[(m * B_SZ + b) * C_DIM + c] = acc * (1.0f / 256.0f);
}

// out[b,n,c] = D[n] * sum_{e in node n} alpha[e,b]*out_e[edge_e,b,c]
// one block per node, all 32 b handled (8 per thread)
__global__ __launch_bounds__(256) void k_out2(
    const int* __restrict__ row_ptr, const int* __restrict__ csr,
    const int* __restrict__ edge_ids, const float* __restrict__ alpha,
    const float* __restrict__ out_e, float* __restrict__ out) {
  const int n = blockIdx.x;
  const int c = threadIdx.x & 63, bq = threadIdx.x >> 6;
  const int rs = row_ptr[n], re = row_ptr[n + 1];
  float acc[8] = {0.f, 0.f, 0.f, 0.f, 0.f, 0.f, 0.f, 0.f};
  for (int i = rs; i < re; ++i) {
    const int e = csr[i];
    const int m = edge_ids[e];
#pragma unroll
    for (int j = 0; j < 8; ++j) {
      const int b = bq * 8 + j;
      acc[j] = fmaf(alpha[e * B_SZ + b], out_e[(m * B_SZ + b) * C_DIM + c],
                    acc[j]);
    }
  }
  const float Dn = (float)(re - rs);
#pragma unroll
  for (int j = 0; j < 8; ++j) {
    const int b = bq * 8 + j;
    out[((size_t)b * N_NODES + n) * C_DIM + c] = Dn * acc[j];
  }
}

// deterministic final reductions + scalar output
__global__ __launch_bounds__(256) void k_fin(const float* __restrict__ essum,
                                             const float* __restrict__ lossbuf,
                                             float* __restrict__ outs) {
  __shared__ float sm[256];
  const int t = threadIdx.x;
  float s = 0.f;
  for (int i = t; i < M_EDGES * B_SZ; i += 256) s += essum[i];
  sm[t] = s;
  __syncthreads();
  for (int o = 128; o > 0; o >>= 1) {
    if (t < o) sm[t] += sm[t + o];
    __syncthreads();
  }
  const float S = sm[0];
  __syncthreads();
  float l = 0.f;
  for (int i = t; i < M_EDGES * M_EDGES; i += 256) l += lossbuf[i];
  sm[t] = l;
  __syncthreads();
  for (int o = 128; o > 0; o >>= 1) {
    if (t < o) sm[t] += sm[t + o];
    __syncthreads();
  }
  if (t == 0) {
    // sum(x_i - x_j) = S - 256*S = -255*S ; mean over E*B*C elements
    const float mean = S * (-255.0f) / 33554432.0f;
    outs[0] = fabsf(mean) + sm[0] * (1.0f / 4225.0f);
  }
}

extern "C" void kernel_launch(void* const* d_in, const int* in_sizes, int n_in,
                              void* d_out, int out_size, void* d_ws,
                              size_t ws_size, hipStream_t stream) {
  (void)in_sizes; (void)n_in; (void)out_size; (void)ws_size;
  const float* x = (const float*)d_in[0];
  const float* weight = (const float*)d_in[1];
  const float* att = (const float*)d_in[2];
  const int* hei = (const int*)d_in[3];
  const int* node_ids = hei;
  const int* edge_ids = hei + E_INC;
  float* out = (float*)d_out;
  float* xw = out;  // reuse d_out as xw scratch; overwritten by k_out2 at the end

  char* wsb = (char*)d_ws;
  float* es_t = (float*)(wsb);                    // 512KB  [m,c,b]
  float* out_e = (float*)(wsb + (512 << 10));     // 512KB  [m,b,c]
  float* s1 = (float*)(wsb + (1024 << 10));       // 512KB
  float* alpha = (float*)(wsb + (1536 << 10));    // 2MB
  float* s2 = (float*)(wsb + (3584 << 10));       // 8KB
  float* nrm2 = (float*)(wsb + (3592 << 10));     // 8KB
  float* essum = (float*)(wsb + (3600 << 10));    // 8KB
  float* lossbuf = (float*)(wsb + (3608 << 10));  // 16KB
  int* row_ptr = (int*)(wsb + (3624 << 10));      // 20KB (4097 ints)
  int* csr = (int*)(wsb + (3644 << 10));          // 64KB

  k_gemm2<<<(B_SZ * N_NODES) / RPB, 64, 0, stream>>>(x, weight, att, xw, s1);
  k_csr<<<1, 1024, 0, stream>>>(node_ids, row_ptr, csr);
  k_edge<<<dim3(M_EDGES, 8), 256, 0, stream>>>(xw, node_ids, att, es_t, s2,
                                               nrm2, essum);
  k_loss2<<<(M_EDGES * M_EDGES) / 4, 256, 0, stream>>>(es_t, nrm2, lossbuf);
  k_alpha<<<N_NODES / 2, 64, 0, stream>>>(row_ptr, csr, edge_ids, s1, s2,
                                          alpha);
  k_oute<<<dim3(M_EDGES, 8), 256, 0, stream>>>(xw, node_ids, alpha, out_e);
  k_out2<<<N_NODES, 256, 0, stream>>>(row_ptr, csr, edge_ids, alpha, out_e,
                                      out);
  k_fin<<<1, 256, 0, stream>>>(essum, lossbuf,
                               out + (size_t)B_SZ * N_NODES * C_DIM);
}

// Round 3
// 124.772 us; speedup vs baseline: 1.3762x; 1.1752x over previous
//
#include <hip/hip_runtime.h>
#include <math.h>

#define B_SZ 32
#define N_NODES 4096
#define C_DIM 64
#define M_EDGES 64
#define DEG 256
#define E_INC 16384
#define NEG_SLOPE 0.2f
#define MARGIN 4.2f

__device__ __forceinline__ float wsum64(float v) {
#pragma unroll
  for (int off = 32; off > 0; off >>= 1) v += __shfl_xor(v, off, 64);
  return v;
}

// watt[k] = sum_c W[k,c]*att[c]   (tiny: 64x64 dot)
__global__ __launch_bounds__(64) void k_watt(const float* __restrict__ w,
                                             const float* __restrict__ att,
                                             float* __restrict__ watt) {
  const int k = threadIdx.x;
  float s = 0.f;
#pragma unroll 8
  for (int c = 0; c < 64; ++c) s = fmaf(w[k * 64 + c], att[c], s);
  watt[k] = s;
}

// s1_t[n*32+b] = dot(x[b,n,:], watt)  -- one streaming pass over x
__global__ __launch_bounds__(256) void k_s1(const float* __restrict__ x,
                                            const float* __restrict__ watt,
                                            float* __restrict__ s1_t) {
  const int lane = threadIdx.x & 63;
  const int wv = threadIdx.x >> 6;
  const int kq = lane & 15, rsub = lane >> 4;
  const float4 wq = ((const float4*)watt)[kq];
  const int r0 = blockIdx.x * 256 + wv * 64;
#pragma unroll 4
  for (int it = 0; it < 16; ++it) {
    const int row = r0 + it * 4 + rsub;
    const float4 xv = ((const float4*)x)[row * 16 + kq];
    float v = xv.x * wq.x + xv.y * wq.y + xv.z * wq.z + xv.w * wq.w;
    v += __shfl_xor(v, 1, 64);
    v += __shfl_xor(v, 2, 64);
    v += __shfl_xor(v, 4, 64);
    v += __shfl_xor(v, 8, 64);
    if (kq == 0) {
      const int n = row & (N_NODES - 1);
      const int b = row >> 12;
      s1_t[n * 32 + b] = v;
    }
  }
}

// node-CSR in one block: LDS count -> wave-shfl scan -> LDS-atomic fill
__global__ __launch_bounds__(1024) void k_csr(const int* __restrict__ node_ids,
                                              int* __restrict__ row_ptr,
                                              int* __restrict__ csr) {
  __shared__ int cnt[N_NODES];
  __shared__ int rp[N_NODES];
  __shared__ int wtot[16];
  const int t = threadIdx.x;
#pragma unroll
  for (int i = 0; i < 4; ++i) cnt[t + 1024 * i] = 0;
  __syncthreads();
#pragma unroll
  for (int i = 0; i < 16; ++i) atomicAdd(&cnt[node_ids[t + 1024 * i]], 1);
  __syncthreads();
  const int c0 = cnt[4 * t], c1 = cnt[4 * t + 1], c2 = cnt[4 * t + 2],
            c3 = cnt[4 * t + 3];
  const int tsum = c0 + c1 + c2 + c3;
  const int lane = t & 63;
  int v = tsum;
#pragma unroll
  for (int off = 1; off < 64; off <<= 1) {
    const int u = __shfl_up(v, off, 64);
    if (lane >= off) v += u;
  }
  if (lane == 63) wtot[t >> 6] = v;
  __syncthreads();
  if (t == 0) {
    int run = 0;
#pragma unroll
    for (int j = 0; j < 16; ++j) {
      const int xx = wtot[j];
      wtot[j] = run;
      run += xx;
    }
  }
  __syncthreads();
  const int base = wtot[t >> 6] + v - tsum;  // exclusive over flattened nodes
  rp[4 * t] = base;
  rp[4 * t + 1] = base + c0;
  rp[4 * t + 2] = base + c0 + c1;
  rp[4 * t + 3] = base + c0 + c1 + c2;
#pragma unroll
  for (int i = 0; i < 4; ++i) cnt[t + 1024 * i] = 0;
  __syncthreads();
#pragma unroll
  for (int i = 0; i < 16; ++i) {
    const int e = t + 1024 * i;
    const int n = node_ids[e];
    const int pos = atomicAdd(&cnt[n], 1);
    csr[rp[n] + pos] = e;
  }
#pragma unroll
  for (int i = 0; i < 4; ++i) row_ptr[t + 1024 * i] = rp[t + 1024 * i];
  if (t == 0) row_ptr[N_NODES] = E_INC;
}

// sum_x over incidences of edge m (in x-space), then fused @W epilogue.
// es_t[m,c,b]; s2/nrm2/essum reductions fused.
__global__ __launch_bounds__(256) void k_edge(
    const float* __restrict__ x, const int* __restrict__ node_ids,
    const float* __restrict__ w, const float* __restrict__ att,
    float* __restrict__ es_t, float* __restrict__ s2,
    float* __restrict__ nrm2, float* __restrict__ essum) {
  __shared__ float wl[4096];
  __shared__ float sxs[4][64];
  const int m = blockIdx.x, bq = blockIdx.y;
  const int k = threadIdx.x & 63;
  const int wv = threadIdx.x >> 6;
  const int b = bq * 4 + wv;
  float4* wl4 = (float4*)wl;
  const float4* w4 = (const float4*)w;
#pragma unroll
  for (int i = 0; i < 4; ++i)
    wl4[threadIdx.x + 256 * i] = w4[threadIdx.x + 256 * i];
  const float* xb = x + (size_t)b * (N_NODES * C_DIM);
  const int ebase = m * DEG;
  float acc = 0.f;
#pragma unroll 16
  for (int i = 0; i < DEG; ++i) {
    const int node = node_ids[ebase + i];
    acc += xb[node * 64 + k];
  }
  sxs[wv][k] = acc;
  __syncthreads();
  const int c = k;
  float es = 0.f;
#pragma unroll 8
  for (int kk = 0; kk < 64; ++kk) es = fmaf(sxs[wv][kk], wl[kk * 64 + c], es);
  es_t[(m * 64 + c) * 32 + b] = es;
  const float sr = wsum64(es * att[64 + c]);
  const float nr = wsum64(es * es);
  const float er = wsum64(es);
  if (c == 0) {
    s2[m * 32 + b] = sr;
    nrm2[m * 32 + b] = nr;
    essum[m * 32 + b] = er;
  }
}

// lossbuf[p] = |mean_b loss_item[k,m,b]|; dist^2 = nk2+nm2-2*inner
__global__ __launch_bounds__(256) void k_loss2(const float* __restrict__ es_t,
                                               const float* __restrict__ nrm2,
                                               float* __restrict__ lossbuf) {
  const int p = blockIdx.x * 4 + (threadIdx.x >> 6);
  const int k = p >> 6, m = p & 63;
  const int b = threadIdx.x & 31;
  float inner = 0.f;
#pragma unroll 8
  for (int c = 0; c < C_DIM; ++c) {
    const float ek = es_t[(k * C_DIM + c) * B_SZ + b];
    const float em = es_t[(m * C_DIM + c) * B_SZ + b];
    inner = fmaf(ek, em, inner);
  }
  const float nk2 = nrm2[k * B_SZ + b];
  const float nm2 = nrm2[m * B_SZ + b];
  const float d2 = fmaxf(nk2 + nm2 - 2.f * inner, 0.f);
  const float dist = sqrtf(d2);
  const float cosv = inner / sqrtf(nk2 * nm2);
  float li = cosv * dist + (1.f - cosv) * fmaxf(MARGIN - dist, 0.f);
#pragma unroll
  for (int off = 16; off > 0; off >>= 1) li += __shfl_xor(li, off, 32);
  if ((threadIdx.x & 63) == 0) lossbuf[p] = fabsf(li * (1.f / 32.f));
}

// per-node online softmax -> alpha[e,b]; edge id derived as e>>8
__global__ __launch_bounds__(256) void k_alpha(
    const int* __restrict__ row_ptr, const int* __restrict__ csr,
    const float* __restrict__ s1_t, const float* __restrict__ s2,
    float* __restrict__ alpha) {
  const int n = blockIdx.x * 8 + (threadIdx.x >> 5);
  const int b = threadIdx.x & 31;
  const int rs = row_ptr[n], re = row_ptr[n + 1];
  if (rs == re) return;
  const float s1v = s1_t[n * 32 + b];
  float mx = -1e30f, S = 0.f;
  for (int i = rs; i < re; ++i) {
    const int e = csr[i];
    float sc = s1v + s2[(e >> 8) * 32 + b];
    sc = sc > 0.f ? sc : NEG_SLOPE * sc;
    const float nm = fmaxf(mx, sc);
    S = S * __expf(mx - nm) + __expf(sc - nm);
    mx = nm;
  }
  const float inv = 1.f / S;
  for (int i = rs; i < re; ++i) {
    const int e = csr[i];
    float sc = s1v + s2[(e >> 8) * 32 + b];
    sc = sc > 0.f ? sc : NEG_SLOPE * sc;
    alpha[e * 32 + b] = __expf(sc - mx) * inv;
  }
}

// alpha-weighted sum_x per edge, fused @W, scaled 1/256 -> out_e_t[m,c,b]
__global__ __launch_bounds__(256) void k_oute(
    const float* __restrict__ x, const int* __restrict__ node_ids,
    const float* __restrict__ w, const float* __restrict__ alpha,
    float* __restrict__ out_e_t) {
  __shared__ float wl[4096];
  __shared__ float sxs[4][64];
  const int m = blockIdx.x, bq = blockIdx.y;
  const int k = threadIdx.x & 63;
  const int wv = threadIdx.x >> 6;
  const int b = bq * 4 + wv;
  float4* wl4 = (float4*)wl;
  const float4* w4 = (const float4*)w;
#pragma unroll
  for (int i = 0; i < 4; ++i)
    wl4[threadIdx.x + 256 * i] = w4[threadIdx.x + 256 * i];
  const float* xb = x + (size_t)b * (N_NODES * C_DIM);
  const int ebase = m * DEG;
  float acc = 0.f;
#pragma unroll 16
  for (int i = 0; i < DEG; ++i) {
    const int e = ebase + i;
    const int node = node_ids[e];
    acc = fmaf(alpha[e * 32 + b], xb[node * 64 + k], acc);
  }
  sxs[wv][k] = acc;
  __syncthreads();
  const int c = k;
  float oc = 0.f;
#pragma unroll 8
  for (int kk = 0; kk < 64; ++kk) oc = fmaf(sxs[wv][kk], wl[kk * 64 + c], oc);
  out_e_t[(m * 64 + c) * 32 + b] = oc * (1.0f / 256.0f);
}

// out[b,n,c] = D[n] * sum_{e in node n} alpha[e,b]*out_e_t[m_e,c,b]
__global__ __launch_bounds__(256) void k_out2(
    const int* __restrict__ row_ptr, const int* __restrict__ csr,
    const float* __restrict__ alpha, const float* __restrict__ out_e_t,
    float* __restrict__ out) {
  const int n = blockIdx.x;
  const int c = threadIdx.x & 63, bq = threadIdx.x >> 6;
  const int rs = row_ptr[n], re = row_ptr[n + 1];
  float4 a0 = {0.f, 0.f, 0.f, 0.f}, a1 = {0.f, 0.f, 0.f, 0.f};
  for (int i = rs; i < re; ++i) {
    const int e = csr[i];
    const int m = e >> 8;
    const float4 al0 = *(const float4*)&alpha[e * 32 + bq * 8];
    const float4 al1 = *(const float4*)&alpha[e * 32 + bq * 8 + 4];
    const float4 v0 = *(const float4*)&out_e_t[(m * 64 + c) * 32 + bq * 8];
    const float4 v1 = *(const float4*)&out_e_t[(m * 64 + c) * 32 + bq * 8 + 4];
    a0.x = fmaf(al0.x, v0.x, a0.x);
    a0.y = fmaf(al0.y, v0.y, a0.y);
    a0.z = fmaf(al0.z, v0.z, a0.z);
    a0.w = fmaf(al0.w, v0.w, a0.w);
    a1.x = fmaf(al1.x, v1.x, a1.x);
    a1.y = fmaf(al1.y, v1.y, a1.y);
    a1.z = fmaf(al1.z, v1.z, a1.z);
    a1.w = fmaf(al1.w, v1.w, a1.w);
  }
  const float Dn = (float)(re - rs);
  const size_t nb = (size_t)n * 64 + c;
  const size_t st = (size_t)N_NODES * 64;
  out[(bq * 8 + 0) * st + nb] = Dn * a0.x;
  out[(bq * 8 + 1) * st + nb] = Dn * a0.y;
  out[(bq * 8 + 2) * st + nb] = Dn * a0.z;
  out[(bq * 8 + 3) * st + nb] = Dn * a0.w;
  out[(bq * 8 + 4) * st + nb] = Dn * a1.x;
  out[(bq * 8 + 5) * st + nb] = Dn * a1.y;
  out[(bq * 8 + 6) * st + nb] = Dn * a1.z;
  out[(bq * 8 + 7) * st + nb] = Dn * a1.w;
}

// deterministic final reductions + scalar output
__global__ __launch_bounds__(256) void k_fin(const float* __restrict__ essum,
                                             const float* __restrict__ lossbuf,
                                             float* __restrict__ outs) {
  __shared__ float sm[256];
  const int t = threadIdx.x;
  float s = 0.f;
  for (int i = t; i < M_EDGES * B_SZ; i += 256) s += essum[i];
  sm[t] = s;
  __syncthreads();
  for (int o = 128; o > 0; o >>= 1) {
    if (t < o) sm[t] += sm[t + o];
    __syncthreads();
  }
  const float S = sm[0];
  __syncthreads();
  float l = 0.f;
  for (int i = t; i < M_EDGES * M_EDGES; i += 256) l += lossbuf[i];
  sm[t] = l;
  __syncthreads();
  for (int o = 128; o > 0; o >>= 1) {
    if (t < o) sm[t] += sm[t + o];
    __syncthreads();
  }
  if (t == 0) {
    const float mean = S * (-255.0f) / 33554432.0f;
    outs[0] = fabsf(mean) + sm[0] * (1.0f / 4225.0f);
  }
}

extern "C" void kernel_launch(void* const* d_in, const int* in_sizes, int n_in,
                              void* d_out, int out_size, void* d_ws,
                              size_t ws_size, hipStream_t stream) {
  (void)in_sizes; (void)n_in; (void)out_size; (void)ws_size;
  const float* x = (const float*)d_in[0];
  const float* weight = (const float*)d_in[1];
  const float* att = (const float*)d_in[2];
  const int* node_ids = (const int*)d_in[3];
  float* out = (float*)d_out;

  char* wsb = (char*)d_ws;
  float* es_t = (float*)(wsb);                    // 512KB [m,c,b]
  float* out_e_t = (float*)(wsb + (512 << 10));   // 512KB [m,c,b]
  float* s1_t = (float*)(wsb + (1024 << 10));     // 512KB [n,b]
  float* alpha = (float*)(wsb + (1536 << 10));    // 2MB   [e,b]
  float* s2 = (float*)(wsb + (3584 << 10));       // 8KB
  float* nrm2 = (float*)(wsb + (3592 << 10));     // 8KB
  float* essum = (float*)(wsb + (3600 << 10));    // 8KB
  float* lossbuf = (float*)(wsb + (3608 << 10));  // 16KB
  int* row_ptr = (int*)(wsb + (3624 << 10));      // 20KB (4097 ints)
  int* csr = (int*)(wsb + (3644 << 10));          // 64KB
  float* watt = (float*)(wsb + (3708 << 10));     // 256B

  k_watt<<<1, 64, 0, stream>>>(weight, att, watt);
  k_csr<<<1, 1024, 0, stream>>>(node_ids, row_ptr, csr);
  k_s1<<<512, 256, 0, stream>>>(x, watt, s1_t);
  k_edge<<<dim3(M_EDGES, 8), 256, 0, stream>>>(x, node_ids, weight, att, es_t,
                                               s2, nrm2, essum);
  k_loss2<<<(M_EDGES * M_EDGES) / 4, 256, 0, stream>>>(es_t, nrm2, lossbuf);
  k_alpha<<<N_NODES / 8, 256, 0, stream>>>(row_ptr, csr, s1_t, s2, alpha);
  k_oute<<<dim3(M_EDGES, 8), 256, 0, stream>>>(x, node_ids, weight, alpha,
                                               out_e_t);
  k_out2<<<N_NODES, 256, 0, stream>>>(row_ptr, csr, alpha, out_e_t, out);
  k_fin<<<1, 256, 0, stream>>>(essum, lossbuf,
                               out + (size_t)B_SZ * N_NODES * C_DIM);
}